// Round 4
// baseline (560.741 us; speedup 1.0000x reference)
//
#include <hip/hip_runtime.h>

// Correlation cost volume, MAX_DISP=4 (81 displacements).
// out[b,(dy+4)*9+(dx+4),y,x] = (1/C) * sum_c first[b,c,y,x]*second[b,c,y+dy,x+dx]
//
// R11: DY-FUSED LDS BLOCK. R7-R10 post-mortems: flat-load structure re-reads
// second 9x / first 18x through L1/L2 (1.77GB request volume for a 132MB
// problem) and the compiler collapses hand-built register pipelines (R10
// VGPR 52 < 68-reg live set). Fix the structure, not the schedule:
//   block = 4x32 px tile, 9 waves, wave w handles dy = w-4. All 9 dy share
//   one LDS-staged tile: first read ONCE from HBM (was 18x), second rows
//   staged 3x across y-neighbors (was 9x). 8-channel chunks, double-buffered
//   LDS, T14 issue-early/write-late staging, ONE barrier per chunk (16 total
//   vs R4/R6's 128 with 9x less compute between).
// Per lane per channel: 5 ds_read_b64 (10-float window) + 1 ds_read_b64
// (first px pair) + 18 FMA. acc = 9 float2.
// Grid 6x32x4 = 768 blocks x 9 waves = 6912 waves; 3 blocks/CU if VGPR<=73
// (2/CU if <=102). launch_bounds(576,5) caps VGPR at 102 -- above the ~70
// live-set estimate, so spill-free (R8 lesson).

#define B_    4
#define C_    128
#define H_    128
#define W_    192
#define HW_   (H_ * W_)
#define CHW_  (C_ * HW_)

#define TX    32
#define TY    4
#define CCH   8             // channels per chunk
#define NCHK  (C_ / CCH)    // 16 chunks
#define SROWS 12            // TY + 8 (dy -4..+4)
#define SCOLS 48            // TX + 8 = 40, padded to 48 (cols 40..47 unused)
#define SVALID 40

__global__ __launch_bounds__(576, 5)
void corr_kernel(const float* __restrict__ first,
                 const float* __restrict__ second,
                 float* __restrict__ out)
{
    __shared__ __align__(16) float lds_sec[2][CCH][SROWS][SCOLS];
    __shared__ __align__(16) float lds_fst[2][CCH][TY][TX];

    const int t  = threadIdx.x;          // 0..575
    const int w  = t >> 6;               // wave index = dyi (0..8)
    const int l  = t & 63;
    const int lx = l & 15;               // 16 lanes across x (2 px each)
    const int ly = l >> 4;               // 0..3 rows
    const int x0 = blockIdx.x * TX;
    const int y0 = blockIdx.y * TY;
    const int b  = blockIdx.z;

    const int X = x0 + 2 * lx;           // this lane's first output x (even)
    const int y = y0 + ly;

    // ---- staging decomposition (computed once) ----
    // sec chunk = [CCH][SROWS][SCOLS] floats = 4608 = 576 thr * 4 float2.
    // float2 index f = t + 576*k  ->  float idx 2t + 1152k. 1152 = 2 channels
    // exactly, so thread t stages the SAME (row,col) in channels c0+{0,2,4,6}.
    const int fi  = 2 * t;
    const int c0  = fi / 576;            // 0 or 1
    const int rem = fi - 576 * c0;
    const int sr  = rem / 48;            // staged row 0..11
    const int sc  = rem - 48 * sr;       // staged col 0..47 (even)
    const int ygs = y0 - 4 + sr;         // global row in second
    const int xgs = x0 - 4 + sc;         // global col in second (even)
    const bool svalid = (ygs >= 0) && (ygs < H_) &&
                        (xgs >= 0) && (xgs < W_) && (sc < SVALID);
    // base for channel 0 (only deref'd via svalid guard):
    const float2* sgp = (const float2*)(second + (size_t)b * CHW_
                                        + (size_t)ygs * W_ + xgs);

    // fst chunk = [CCH][TY][TX] floats = 1024 = 512 thr * 1 float2.
    const bool fstage = (t < 512);
    const int fc   = t >> 6;             // 0..7 (channel) for t<512
    const int fr   = (t >> 4) & 3;       // row 0..3
    const int fcol = 2 * (t & 15);       // col 0..30 (even)
    const float2* fgp = (const float2*)(first + (size_t)b * CHW_
                                        + (size_t)(y0 + fr) * W_ + (x0 + fcol));

    const float2 z2 = make_float2(0.f, 0.f);

// issue global loads for chunk with channel base CB into registers (T14 early)
#define ISSUE(CB, S0, S1, S2, S3, F0)                                    \
    {                                                                    \
        const float2* sp = sgp + (size_t)((CB) + c0) * (HW_ / 2);        \
        S0 = svalid ? sp[(size_t)0 * HW_] : z2;                          \
        S1 = svalid ? sp[(size_t)1 * HW_] : z2;                          \
        S2 = svalid ? sp[(size_t)2 * HW_] : z2;                          \
        S3 = svalid ? sp[(size_t)3 * HW_] : z2;                          \
        F0 = fstage ? fgp[(size_t)((CB) + fc) * (HW_ / 2)] : z2;         \
    }

// write staged registers into LDS buffer BUF (T14 late; vmcnt waits inserted
// by compiler at first use)
#define WRITE(BUF, S0, S1, S2, S3, F0)                                   \
    {                                                                    \
        *(float2*)&lds_sec[BUF][c0 + 0][sr][sc] = S0;                    \
        *(float2*)&lds_sec[BUF][c0 + 2][sr][sc] = S1;                    \
        *(float2*)&lds_sec[BUF][c0 + 4][sr][sc] = S2;                    \
        *(float2*)&lds_sec[BUF][c0 + 6][sr][sc] = S3;                    \
        if (fstage) *(float2*)&lds_fst[BUF][fc][fr][fcol] = F0;          \
    }

    float2 acc[9];
    #pragma unroll
    for (int i = 0; i < 9; ++i) acc[i] = z2;

    // prologue: stage chunk 0 into buffer 0
    {
        float2 s0, s1, s2, s3, f0;
        ISSUE(0, s0, s1, s2, s3, f0)
        WRITE(0, s0, s1, s2, s3, f0)
    }
    __syncthreads();

    #pragma unroll 1
    for (int k = 0; k < NCHK; ++k) {
        const int cur = k & 1;
        float2 s0, s1, s2, s3, f0;
        if (k + 1 < NCHK) {
            ISSUE((k + 1) * CCH, s0, s1, s2, s3, f0)   // loads fly over compute
        }

        // compute 8 channels from buf[cur]: wave w reads staged row ly+w,
        // i.e. second row y + (w-4); window cols 2*lx .. 2*lx+9.
        #pragma unroll
        for (int c = 0; c < CCH; ++c) {
            float wv[10];
            #pragma unroll
            for (int k2 = 0; k2 < 5; ++k2)
                *(float2*)(wv + 2 * k2) =
                    *(const float2*)&lds_sec[cur][c][ly + w][2 * lx + 2 * k2];
            const float2 fch = *(const float2*)&lds_fst[cur][c][ly][2 * lx];
            #pragma unroll
            for (int dxi = 0; dxi < 9; ++dxi) {
                // out px X+p, dx=dxi-4 -> staged col 2*lx + p + dxi = wv[p+dxi]
                acc[dxi].x += fch.x * wv[dxi];
                acc[dxi].y += fch.y * wv[dxi + 1];
            }
        }

        if (k + 1 < NCHK) {
            WRITE(cur ^ 1, s0, s1, s2, s3, f0)         // into the idle buffer
        }
        __syncthreads();   // writes to buf[cur^1] visible; reads of buf[cur] done
    }

    // epilogue: out[b, w*9 + dxi, y, X..X+1]
    const float scale = 1.0f / (float)C_;
    float* ob = out + ((size_t)b * 81 + (size_t)w * 9) * HW_
                    + (size_t)y * W_ + X;
    #pragma unroll
    for (int dxi = 0; dxi < 9; ++dxi) {
        float2 r2 = acc[dxi];
        r2.x *= scale; r2.y *= scale;
        *(float2*)(ob + (size_t)dxi * HW_) = r2;
    }
}

extern "C" void kernel_launch(void* const* d_in, const int* in_sizes, int n_in,
                              void* d_out, int out_size, void* d_ws, size_t ws_size,
                              hipStream_t stream) {
    const float* first  = (const float*)d_in[0];
    const float* second = (const float*)d_in[1];
    float* out = (float*)d_out;

    dim3 grid(W_ / TX, H_ / TY, B_);     // 6 x 32 x 4 = 768 blocks
    dim3 block(576);                     // 9 waves: one per dy
    corr_kernel<<<grid, block, 0, stream>>>(first, second, out);
}

// Round 5
// 260.848 us; speedup vs baseline: 2.1497x; 2.1497x over previous
//
#include <hip/hip_runtime.h>

// Correlation cost volume, MAX_DISP=4 (81 displacements).
// out[b,(dy+4)*9+(dx+4),y,x] = (1/C) * sum_c first[b,c,y,x]*second[b,c,y+dy,x+dx]
//
// R12 = R11 (dy-fused LDS block) minus the spill.
// R11 post-mortem: WRITE_SIZE 964MB = 28x output -> scratch spill. The fully
// unrolled 8-channel compute loop hoisted ~96 floats of LDS reads past the
// 102-VGPR cap -> regalloc spilled the loop state (VALUBusy 5.8%). The dy-
// fusion thesis (first read 1x from HBM, second 3x, 16 barriers) was never
// actually tested. Fixes:
//  1. #pragma unroll 2 on the channel loop: only 2 channels of LDS reads in
//     flight (~24 floats); live set ~65 regs. TLP (18-27 waves/CU) hides LDS
//     latency instead of intra-wave hoisting.
//  2. first read from GLOBAL per thread (own px pair, L1 broadcast across the
//     9 waves -- R7-proven), drops lds_fst: LDS 45->36KB, fewer staging regs,
//     no fst bank conflicts.
// launch_bounds(576,6): VGPR cap 85 > ~65 live set (R8 lesson: cap above the
// live set), guarantees >=2 blocks/CU; 3 blocks (84% occ) if alloc <=73.
// Known 4-way bank conflict on the even-stride float2 window reads (~1.58x on
// the LDS pipe, m136) -- structural to even strides, accepted this round.

#define B_    4
#define C_    128
#define H_    128
#define W_    192
#define HW_   (H_ * W_)
#define CHW_  (C_ * HW_)

#define TX    32
#define TY    4
#define CCH   8             // channels per chunk
#define NCHK  (C_ / CCH)    // 16 chunks
#define SROWS 12            // TY + 8 (dy -4..+4)
#define SCOLS 48            // TX + 8 = 40, padded to 48 (cols 40..47 zeroed)
#define SVALID 40

__global__ __launch_bounds__(576, 6)
void corr_kernel(const float* __restrict__ first,
                 const float* __restrict__ second,
                 float* __restrict__ out)
{
    __shared__ __align__(16) float lds_sec[2][CCH][SROWS][SCOLS];

    const int t  = threadIdx.x;          // 0..575
    const int w  = t >> 6;               // wave index = dyi (0..8)
    const int l  = t & 63;
    const int lx = l & 15;               // 16 lanes across x (2 px each)
    const int ly = l >> 4;               // 0..3 rows
    const int x0 = blockIdx.x * TX;
    const int y0 = blockIdx.y * TY;
    const int b  = blockIdx.z;

    const int X = x0 + 2 * lx;           // this lane's first output x (even)
    const int y = y0 + ly;

    // ---- second staging decomposition ----
    // sec chunk = [CCH][SROWS][SCOLS] floats = 4608 = 576 thr * 4 float2.
    // float2 index f = t + 576*k -> float idx 2t + 1152k; 1152 = 2 channels,
    // so thread t stages the SAME (row,col) in channels c0+{0,2,4,6}.
    const int fi  = 2 * t;
    const int c0  = fi / 576;            // 0 or 1
    const int rem = fi - 576 * c0;
    const int sr  = rem / 48;            // staged row 0..11
    const int sc  = rem - 48 * sr;       // staged col 0..46 (even)
    const int ygs = y0 - 4 + sr;         // global row in second
    const int xgs = x0 - 4 + sc;         // global col in second (even)
    const bool svalid = (ygs >= 0) && (ygs < H_) &&
                        (xgs >= 0) && (xgs < W_) && (sc < SVALID);
    // base for channel c0 (only deref'd when svalid):
    const float2* sgp = (const float2*)(second + (size_t)b * CHW_
                                        + (size_t)ygs * W_ + xgs);

    // per-thread first pointer: own px pair, shared by all 9 waves via L1
    const float* fp = first + (size_t)b * CHW_ + (size_t)y * W_ + X;

    const float2 z2 = make_float2(0.f, 0.f);

// issue global loads for chunk with channel base CB (T14 early)
#define ISSUE(CB, S0, S1, S2, S3)                                        \
    {                                                                    \
        const float2* sp = sgp + (size_t)((CB) + c0) * (HW_ / 2);        \
        S0 = svalid ? sp[(size_t)0 * HW_] : z2;                          \
        S1 = svalid ? sp[(size_t)1 * HW_] : z2;                          \
        S2 = svalid ? sp[(size_t)2 * HW_] : z2;                          \
        S3 = svalid ? sp[(size_t)3 * HW_] : z2;                          \
    }

// write staged registers into LDS buffer BUF (T14 late)
#define WRITE(BUF, S0, S1, S2, S3)                                       \
    {                                                                    \
        *(float2*)&lds_sec[BUF][c0 + 0][sr][sc] = S0;                    \
        *(float2*)&lds_sec[BUF][c0 + 2][sr][sc] = S1;                    \
        *(float2*)&lds_sec[BUF][c0 + 4][sr][sc] = S2;                    \
        *(float2*)&lds_sec[BUF][c0 + 6][sr][sc] = S3;                    \
    }

    float2 acc[9];
    #pragma unroll
    for (int i = 0; i < 9; ++i) acc[i] = z2;

    // prologue: stage chunk 0 into buffer 0
    {
        float2 s0, s1, s2, s3;
        ISSUE(0, s0, s1, s2, s3)
        WRITE(0, s0, s1, s2, s3)
    }
    __syncthreads();

    #pragma unroll 1
    for (int k = 0; k < NCHK; ++k) {
        const int cur = k & 1;
        float2 s0, s1, s2, s3;
        if (k + 1 < NCHK) {
            ISSUE((k + 1) * CCH, s0, s1, s2, s3)   // loads fly over compute
        }

        // compute 8 channels from buf[cur]: wave w reads staged row ly+w
        // (= second row y + (w-4)); window cols 2*lx .. 2*lx+9.
        // unroll 2: keep only ~2 channels of LDS reads in flight (anti-spill).
        #pragma unroll 2
        for (int c = 0; c < CCH; ++c) {
            const float2 fch = *(const float2*)(fp
                                + (size_t)(k * CCH + c) * HW_);
            float wv[10];
            #pragma unroll
            for (int k2 = 0; k2 < 5; ++k2)
                *(float2*)(wv + 2 * k2) =
                    *(const float2*)&lds_sec[cur][c][ly + w][2 * lx + 2 * k2];
            #pragma unroll
            for (int dxi = 0; dxi < 9; ++dxi) {
                // out px X+p, dx=dxi-4 -> staged col 2*lx+p+dxi = wv[p+dxi]
                acc[dxi].x += fch.x * wv[dxi];
                acc[dxi].y += fch.y * wv[dxi + 1];
            }
        }

        if (k + 1 < NCHK) {
            WRITE(cur ^ 1, s0, s1, s2, s3)         // into the idle buffer
        }
        __syncthreads();   // buf[cur^1] visible; reads of buf[cur] done
    }

    // epilogue: out[b, w*9 + dxi, y, X..X+1]
    const float scale = 1.0f / (float)C_;
    float* ob = out + ((size_t)b * 81 + (size_t)w * 9) * HW_
                    + (size_t)y * W_ + X;
    #pragma unroll
    for (int dxi = 0; dxi < 9; ++dxi) {
        float2 r2 = acc[dxi];
        r2.x *= scale; r2.y *= scale;
        *(float2*)(ob + (size_t)dxi * HW_) = r2;
    }
}

extern "C" void kernel_launch(void* const* d_in, const int* in_sizes, int n_in,
                              void* d_out, int out_size, void* d_ws, size_t ws_size,
                              hipStream_t stream) {
    const float* first  = (const float*)d_in[0];
    const float* second = (const float*)d_in[1];
    float* out = (float*)d_out;

    dim3 grid(W_ / TX, H_ / TY, B_);     // 6 x 32 x 4 = 768 blocks
    dim3 block(576);                     // 9 waves: one per dy
    corr_kernel<<<grid, block, 0, stream>>>(first, second, out);
}

// Round 8
// 195.901 us; speedup vs baseline: 2.8624x; 1.3315x over previous
//
#include <hip/hip_runtime.h>
#include <stdint.h>

// Correlation cost volume, MAX_DISP=4 (81 displacements).
// out[b,(dy+4)*9+(dx+4),y,x] = (1/C) * sum_c first[b,c,y,x]*second[b,c,y+dy,x+dx]
//
// R15: PHYSICAL-REGISTER PIPELINE. R14 post-mortem: loop-carried asm outputs
// get RA phi-copies at the back-edge; the copies read VMEM dest regs while
// loads are in flight (no HW interlock without s_waitcnt) -> garbage. The
// compiler's virtual-reg model cannot express async register writes. Fix:
// pin ALL pipeline state in hard-coded physical VGPRs:
//   v32-v47  slot A (window 12 floats = v32-43, first = v44-47)
//   v48-v63  slot B,  v64-v79 slot C,  v80-v95 slot D
//   v96-v131 acc (acc[dxi] = v[96+4*dxi .. +3])
// Loads, FMAs, waits all volatile asm on named regs; EVERY loop asm clobbers
// v32-v131 so no compiler value can live there (values live across an asm
// avoid its clobbers; there is no other vector C code in the loop).
// Depth-4, steady s_waitcnt vmcnt(12) (never 0), tail 12/8/4/0.
// Boundary masking is OUT of the hot loop: invalid lanes point at a BSS-zero
// device page with per-lane stride 0 -> they load 0.0 forever. No cndmask,
// no LDS, no barriers. R7 grid (1728 x 128), natural mapping (R9 lesson).
// launch_bounds(128,3): VGPR cap 170 > ~150 used (R8/R11 lesson).

#define B_    4
#define C_    128
#define H_    128
#define W_    192
#define HW_   (H_ * W_)
#define CHW_  (C_ * HW_)
#define CHB   ((uint64_t)HW_ * 4)   // channel stride in bytes

#define TX    64
#define TY    8

__device__ __align__(16) float ZPAGE[4];   // BSS: guaranteed zero

#define PIPE_CLOB \
    "v32","v33","v34","v35","v36","v37","v38","v39","v40","v41", \
    "v42","v43","v44","v45","v46","v47","v48","v49","v50","v51", \
    "v52","v53","v54","v55","v56","v57","v58","v59","v60","v61", \
    "v62","v63","v64","v65","v66","v67","v68","v69","v70","v71", \
    "v72","v73","v74","v75","v76","v77","v78","v79","v80","v81", \
    "v82","v83","v84","v85","v86","v87","v88","v89","v90","v91", \
    "v92","v93","v94","v95","v96","v97","v98","v99","v100","v101", \
    "v102","v103","v104","v105","v106","v107","v108","v109","v110","v111", \
    "v112","v113","v114","v115","v116","v117","v118","v119","v120","v121", \
    "v122","v123","v124","v125","v126","v127","v128","v129","v130","v131"

#define FM(a,f,w) "v_fmac_f32 v" #a ", v" #f ", v" #w "\n\t"
#define ZM(n)     "v_mov_b32 v" #n ", 0\n\t"

// acc[dxi].p += first.p * win[dxi+p]; acc reg = 96+4*dxi+p, f = F+p, w = W+dxi+p
#define FMA_A asm volatile( \
    FM(96,44,32)  FM(97,45,33)  FM(98,46,34)  FM(99,47,35)   \
    FM(100,44,33) FM(101,45,34) FM(102,46,35) FM(103,47,36)  \
    FM(104,44,34) FM(105,45,35) FM(106,46,36) FM(107,47,37)  \
    FM(108,44,35) FM(109,45,36) FM(110,46,37) FM(111,47,38)  \
    FM(112,44,36) FM(113,45,37) FM(114,46,38) FM(115,47,39)  \
    FM(116,44,37) FM(117,45,38) FM(118,46,39) FM(119,47,40)  \
    FM(120,44,38) FM(121,45,39) FM(122,46,40) FM(123,47,41)  \
    FM(124,44,39) FM(125,45,40) FM(126,46,41) FM(127,47,42)  \
    FM(128,44,40) FM(129,45,41) FM(130,46,42) FM(131,47,43)  \
    ::: PIPE_CLOB)

#define FMA_B asm volatile( \
    FM(96,60,48)  FM(97,61,49)  FM(98,62,50)  FM(99,63,51)   \
    FM(100,60,49) FM(101,61,50) FM(102,62,51) FM(103,63,52)  \
    FM(104,60,50) FM(105,61,51) FM(106,62,52) FM(107,63,53)  \
    FM(108,60,51) FM(109,61,52) FM(110,62,53) FM(111,63,54)  \
    FM(112,60,52) FM(113,61,53) FM(114,62,54) FM(115,63,55)  \
    FM(116,60,53) FM(117,61,54) FM(118,62,55) FM(119,63,56)  \
    FM(120,60,54) FM(121,61,55) FM(122,62,56) FM(123,63,57)  \
    FM(124,60,55) FM(125,61,56) FM(126,62,57) FM(127,63,58)  \
    FM(128,60,56) FM(129,61,57) FM(130,62,58) FM(131,63,59)  \
    ::: PIPE_CLOB)

#define FMA_C asm volatile( \
    FM(96,76,64)  FM(97,77,65)  FM(98,78,66)  FM(99,79,67)   \
    FM(100,76,65) FM(101,77,66) FM(102,78,67) FM(103,79,68)  \
    FM(104,76,66) FM(105,77,67) FM(106,78,68) FM(107,79,69)  \
    FM(108,76,67) FM(109,77,68) FM(110,78,69) FM(111,79,70)  \
    FM(112,76,68) FM(113,77,69) FM(114,78,70) FM(115,79,71)  \
    FM(116,76,69) FM(117,77,70) FM(118,78,71) FM(119,79,72)  \
    FM(120,76,70) FM(121,77,71) FM(122,78,72) FM(123,79,73)  \
    FM(124,76,71) FM(125,77,72) FM(126,78,73) FM(127,79,74)  \
    FM(128,76,72) FM(129,77,73) FM(130,78,74) FM(131,79,75)  \
    ::: PIPE_CLOB)

#define FMA_D asm volatile( \
    FM(96,92,80)  FM(97,93,81)  FM(98,94,82)  FM(99,95,83)   \
    FM(100,92,81) FM(101,93,82) FM(102,94,83) FM(103,95,84)  \
    FM(104,92,82) FM(105,93,83) FM(106,94,84) FM(107,95,85)  \
    FM(108,92,83) FM(109,93,84) FM(110,94,85) FM(111,95,86)  \
    FM(112,92,84) FM(113,93,85) FM(114,94,86) FM(115,95,87)  \
    FM(116,92,85) FM(117,93,86) FM(118,94,87) FM(119,95,88)  \
    FM(120,92,86) FM(121,93,87) FM(122,94,88) FM(123,95,89)  \
    FM(124,92,87) FM(125,93,88) FM(126,94,89) FM(127,95,90)  \
    FM(128,92,88) FM(129,93,89) FM(130,94,90) FM(131,95,91)  \
    ::: PIPE_CLOB)

#define ISSUE_A asm volatile( \
    "global_load_dwordx4 v[32:35], %0, off\n\t" \
    "global_load_dwordx4 v[36:39], %1, off\n\t" \
    "global_load_dwordx4 v[40:43], %2, off\n\t" \
    "global_load_dwordx4 v[44:47], %3, off" \
    :: "v"(q0), "v"(q1), "v"(q2), "v"(qf) : PIPE_CLOB)
#define ISSUE_B asm volatile( \
    "global_load_dwordx4 v[48:51], %0, off\n\t" \
    "global_load_dwordx4 v[52:55], %1, off\n\t" \
    "global_load_dwordx4 v[56:59], %2, off\n\t" \
    "global_load_dwordx4 v[60:63], %3, off" \
    :: "v"(q0), "v"(q1), "v"(q2), "v"(qf) : PIPE_CLOB)
#define ISSUE_C asm volatile( \
    "global_load_dwordx4 v[64:67], %0, off\n\t" \
    "global_load_dwordx4 v[68:71], %1, off\n\t" \
    "global_load_dwordx4 v[72:75], %2, off\n\t" \
    "global_load_dwordx4 v[76:79], %3, off" \
    :: "v"(q0), "v"(q1), "v"(q2), "v"(qf) : PIPE_CLOB)
#define ISSUE_D asm volatile( \
    "global_load_dwordx4 v[80:83], %0, off\n\t" \
    "global_load_dwordx4 v[84:87], %1, off\n\t" \
    "global_load_dwordx4 v[88:91], %2, off\n\t" \
    "global_load_dwordx4 v[92:95], %3, off" \
    :: "v"(q0), "v"(q1), "v"(q2), "v"(qf) : PIPE_CLOB)

#define WAITVM(N) \
    asm volatile("s_waitcnt vmcnt(" #N ")" ::: "memory"); \
    __builtin_amdgcn_sched_barrier(0);

#define ADV  { q0 += s0; q1 += s1; q2 += s2; qf += CHB; }

__global__ __launch_bounds__(128, 3)
void corr_kernel(const float* __restrict__ first,
                 const float* __restrict__ second,
                 float* __restrict__ out)
{
    const int t  = threadIdx.x;
    const int tx = t & 15;       // 0..15 (4 px each)
    const int ty = t >> 4;       // 0..7
    const int x0 = blockIdx.x * TX;
    const int y0 = blockIdx.y * TY;
    const int bz = blockIdx.z;   // b*9 + (dy+4)
    const int b  = bz / 9;
    const int dyi = bz - 9 * b;  // 0..8
    const int dy  = dyi - 4;

    const int X = x0 + 4 * tx;
    const int y = y0 + ty;
    const int ys = y + dy;       // source row in second

    const float* fptr  = first  + (size_t)b * CHW_ + (size_t)y * W_ + X;
    const float* wbase = second + (size_t)b * CHW_ + (size_t)ys * W_ + (X - 4);

    const bool rowv = (ys >= 0) && (ys < H_);
    const bool v0 = rowv && (X >= 4);          // chunk [X-4, X)
    const bool v1 = rowv;                      // chunk [X,   X+4)
    const bool v2 = rowv && (X <= W_ - 8);     // chunk [X+4, X+8)

    // invalid lanes: load forever from the zero page (stride 0) -> contribute 0
    const uint64_t zp = (uint64_t)(uintptr_t)ZPAGE;
    uint64_t q0 = v0 ? (uint64_t)(uintptr_t)(wbase)     : zp;
    uint64_t q1 = v1 ? (uint64_t)(uintptr_t)(wbase + 4) : zp;
    uint64_t q2 = v2 ? (uint64_t)(uintptr_t)(wbase + 8) : zp;
    uint64_t qf = (uint64_t)(uintptr_t)fptr;
    const uint64_t s0 = v0 ? CHB : 0;
    const uint64_t s1 = v1 ? CHB : 0;
    const uint64_t s2 = v2 ? CHB : 0;

    // zero the accumulator block v96-v131
    asm volatile(
        ZM(96)  ZM(97)  ZM(98)  ZM(99)  ZM(100) ZM(101) ZM(102) ZM(103)
        ZM(104) ZM(105) ZM(106) ZM(107) ZM(108) ZM(109) ZM(110) ZM(111)
        ZM(112) ZM(113) ZM(114) ZM(115) ZM(116) ZM(117) ZM(118) ZM(119)
        ZM(120) ZM(121) ZM(122) ZM(123) ZM(124) ZM(125) ZM(126) ZM(127)
        ZM(128) ZM(129) ZM(130) ZM(131)
        ::: PIPE_CLOB);

    // prologue: channels 0..3 -> 16 loads in flight
    ISSUE_A; ADV
    ISSUE_B; ADV
    ISSUE_C; ADV
    ISSUE_D; ADV

    // steady state: consume ch c, refill ch c+4; vmcnt(12) = slot landed.
    #pragma unroll 1
    for (int it = 0; it < 31; ++it) {
        WAITVM(12) FMA_A; ISSUE_A; ADV
        WAITVM(12) FMA_B; ISSUE_B; ADV
        WAITVM(12) FMA_C; ISSUE_C; ADV
        WAITVM(12) FMA_D; ISSUE_D; ADV
    }
    // tail: channels 124..127, drain 12/8/4/0
    WAITVM(12) FMA_A;
    WAITVM(8)  FMA_B;
    WAITVM(4)  FMA_C;
    WAITVM(0)  FMA_D;

    // read out acc (clobber sources so outputs can't be allocated into them)
    float rr[36];
    asm volatile(
        "v_mov_b32 %0, v96\n\t"  "v_mov_b32 %1, v97\n\t"
        "v_mov_b32 %2, v98\n\t"  "v_mov_b32 %3, v99\n\t"
        "v_mov_b32 %4, v100\n\t" "v_mov_b32 %5, v101\n\t"
        "v_mov_b32 %6, v102\n\t" "v_mov_b32 %7, v103\n\t"
        "v_mov_b32 %8, v104\n\t" "v_mov_b32 %9, v105\n\t"
        "v_mov_b32 %10, v106\n\t" "v_mov_b32 %11, v107\n\t"
        "v_mov_b32 %12, v108\n\t" "v_mov_b32 %13, v109\n\t"
        "v_mov_b32 %14, v110\n\t" "v_mov_b32 %15, v111\n\t"
        "v_mov_b32 %16, v112\n\t" "v_mov_b32 %17, v113"
        : "=v"(rr[0]), "=v"(rr[1]), "=v"(rr[2]), "=v"(rr[3]),
          "=v"(rr[4]), "=v"(rr[5]), "=v"(rr[6]), "=v"(rr[7]),
          "=v"(rr[8]), "=v"(rr[9]), "=v"(rr[10]), "=v"(rr[11]),
          "=v"(rr[12]), "=v"(rr[13]), "=v"(rr[14]), "=v"(rr[15]),
          "=v"(rr[16]), "=v"(rr[17])
        :: "v96","v97","v98","v99","v100","v101","v102","v103","v104",
           "v105","v106","v107","v108","v109","v110","v111","v112","v113");
    asm volatile(
        "v_mov_b32 %0, v114\n\t" "v_mov_b32 %1, v115\n\t"
        "v_mov_b32 %2, v116\n\t" "v_mov_b32 %3, v117\n\t"
        "v_mov_b32 %4, v118\n\t" "v_mov_b32 %5, v119\n\t"
        "v_mov_b32 %6, v120\n\t" "v_mov_b32 %7, v121\n\t"
        "v_mov_b32 %8, v122\n\t" "v_mov_b32 %9, v123\n\t"
        "v_mov_b32 %10, v124\n\t" "v_mov_b32 %11, v125\n\t"
        "v_mov_b32 %12, v126\n\t" "v_mov_b32 %13, v127\n\t"
        "v_mov_b32 %14, v128\n\t" "v_mov_b32 %15, v129\n\t"
        "v_mov_b32 %16, v130\n\t" "v_mov_b32 %17, v131"
        : "=v"(rr[18]), "=v"(rr[19]), "=v"(rr[20]), "=v"(rr[21]),
          "=v"(rr[22]), "=v"(rr[23]), "=v"(rr[24]), "=v"(rr[25]),
          "=v"(rr[26]), "=v"(rr[27]), "=v"(rr[28]), "=v"(rr[29]),
          "=v"(rr[30]), "=v"(rr[31]), "=v"(rr[32]), "=v"(rr[33]),
          "=v"(rr[34]), "=v"(rr[35])
        :: "v114","v115","v116","v117","v118","v119","v120","v121","v122",
           "v123","v124","v125","v126","v127","v128","v129","v130","v131");

    // epilogue: out[b, dyi*9 + dxi, y, X..X+3]
    const float scale = 1.0f / (float)C_;
    #pragma unroll
    for (int dxi = 0; dxi < 9; ++dxi) {
        const int d = dyi * 9 + dxi;
        float4 r;
        r.x = rr[4 * dxi + 0] * scale;
        r.y = rr[4 * dxi + 1] * scale;
        r.z = rr[4 * dxi + 2] * scale;
        r.w = rr[4 * dxi + 3] * scale;
        *(float4*)(out + ((size_t)b * 81 + d) * HW_ + (size_t)y * W_ + X) = r;
    }
}

extern "C" void kernel_launch(void* const* d_in, const int* in_sizes, int n_in,
                              void* d_out, int out_size, void* d_ws, size_t ws_size,
                              hipStream_t stream) {
    const float* first  = (const float*)d_in[0];
    const float* second = (const float*)d_in[1];
    float* out = (float*)d_out;

    dim3 grid(W_ / TX, H_ / TY, B_ * 9);   // 3 x 16 x 36 = 1728 blocks
    dim3 block(128);
    corr_kernel<<<grid, block, 0, stream>>>(first, second, out);
}